// Round 2
// baseline (1403.400 us; speedup 1.0000x reference)
//
#include <hip/hip_runtime.h>
#include <math.h>

#define E_    3
#define QE_   60000
#define QTOT  180000      // E_*QE_
#define P_    40
#define H_    20
#define NIMG_ 1800
#define NNZ_  14400000
#define BLK   256
#define NB    704         // ceil(QTOT/BLK)

// row-bucket binning for the sparse force scatter
#define RBITS   12
#define RWIN    4096                  // floats per row window (16 KB LDS)
#define NBIN    1758                  // ceil(7.2M / 4096)
#define CITEMS  16384                 // nnz items per binning block
#define NCB     879                   // ceil(NNZ_/CITEMS)

// ---------------- zero init (d_out is poisoned 0xAA every launch) -----------
__global__ void zero_kernel(float* __restrict__ out, int n) {
    int i = blockIdx.x * blockDim.x + threadIdx.x;
    if (i < n) out[i] = 0.0f;
}

// ---------------- stable counting sort for atom ranks ----------------------
// g_hist layout: bucket-major g_hist[v*NB + b]
__global__ void hist_kernel(const int* __restrict__ img, int* __restrict__ g_hist) {
    __shared__ int h[NIMG_];
    const int t = threadIdx.x, b = blockIdx.x;
    for (int v = t; v < NIMG_; v += BLK) h[v] = 0;
    __syncthreads();
    int a = b * BLK + t;
    if (a < QTOT) atomicAdd(&h[img[a]], 1);
    __syncthreads();
    for (int v = t; v < NIMG_; v += BLK) g_hist[v * NB + b] = h[v];
}

__global__ void scan_blocks_kernel(int* __restrict__ g_hist, int* __restrict__ g_total) {
    __shared__ int s[BLK];
    const int v = blockIdx.x, t = threadIdx.x;
    int carry = 0;
    for (int c = 0; c < NB; c += BLK) {
        int idx = c + t;
        int val = (idx < NB) ? g_hist[v * NB + idx] : 0;
        s[t] = val; __syncthreads();
        for (int off = 1; off < BLK; off <<= 1) {
            int tmp = (t >= off) ? s[t - off] : 0;
            __syncthreads();
            s[t] += tmp;
            __syncthreads();
        }
        int excl = s[t] - val;
        int tot  = s[BLK - 1];
        if (idx < NB) g_hist[v * NB + idx] = carry + excl;
        carry += tot;
        __syncthreads();
    }
    if (t == 0) g_total[v] = carry;
}

__global__ void scan_buckets_kernel(const int* __restrict__ g_total, int* __restrict__ g_base) {
    __shared__ int s[BLK];
    const int t = threadIdx.x;
    int carry = 0;
    for (int c = 0; c < NIMG_; c += BLK) {
        int idx = c + t;
        int val = (idx < NIMG_) ? g_total[idx] : 0;
        s[t] = val; __syncthreads();
        for (int off = 1; off < BLK; off <<= 1) {
            int tmp = (t >= off) ? s[t - off] : 0;
            __syncthreads();
            s[t] += tmp;
            __syncthreads();
        }
        if (idx < NIMG_) g_base[idx] = carry + (s[t] - val);
        carry += s[BLK - 1];
        __syncthreads();
    }
}

__global__ void rank_kernel(const int* __restrict__ img, const int* __restrict__ g_hist,
                            const int* __restrict__ g_base, int* __restrict__ rank) {
    __shared__ int simg[BLK];
    const int t = threadIdx.x, b = blockIdx.x;
    int a = b * BLK + t;
    int v = (a < QTOT) ? img[a] : -1;
    simg[t] = v;
    __syncthreads();
    if (a < QTOT) {
        int local = 0;
        for (int j = 0; j < BLK; ++j) {
            if (j < t && simg[j] == v) local++;
        }
        rank[a] = g_base[v] + g_hist[v * NB + b] + local;
    }
}

// ---------------- per-atom MLP forward + backward ---------------------------
__global__ __launch_bounds__(BLK) void mlp_kernel(
    const float* __restrict__ fps, const float* __restrict__ W1, const float* __restrict__ b1,
    const float* __restrict__ W2, const float* __restrict__ b2, const float* __restrict__ W3,
    const float* __restrict__ b3, const int* __restrict__ img, const int* __restrict__ rank,
    float* __restrict__ energy, float* __restrict__ dEflat)
{
    __shared__ float sW1[P_ * H_], sW2[H_ * H_], sW3[H_], sB1[H_], sB2[H_];
    __shared__ float sB3;
    const int e = blockIdx.y;
    const int t = threadIdx.x;
    for (int i = t; i < P_ * H_; i += BLK) sW1[i] = W1[e * P_ * H_ + i];
    for (int i = t; i < H_ * H_; i += BLK) sW2[i] = W2[e * H_ * H_ + i];
    if (t < H_) { sW3[t] = W3[e * H_ + t]; sB1[t] = b1[e * H_ + t]; sB2[t] = b2[e * H_ + t]; }
    if (t == 0) sB3 = b3[e];
    __syncthreads();

    int q = blockIdx.x * BLK + t;
    if (q >= QE_) return;
    int a = e * QE_ + q;

    const float* xp = fps + (size_t)a * P_;
    float x[P_];
    #pragma unroll
    for (int p = 0; p < P_; p += 4) {
        float4 v4 = *(const float4*)(xp + p);
        x[p] = v4.x; x[p+1] = v4.y; x[p+2] = v4.z; x[p+3] = v4.w;
    }

    float h1v[H_], h2v[H_];
    #pragma unroll
    for (int i = 0; i < H_; ++i) {
        float z = sB1[i];
        #pragma unroll
        for (int p = 0; p < P_; ++p) z += x[p] * sW1[p * H_ + i];
        h1v[i] = tanhf(z);
    }
    #pragma unroll
    for (int i = 0; i < H_; ++i) {
        float z = sB2[i];
        #pragma unroll
        for (int j = 0; j < H_; ++j) z += h1v[j] * sW2[j * H_ + i];
        h2v[i] = tanhf(z);
    }
    float ea = sB3;
    #pragma unroll
    for (int i = 0; i < H_; ++i) ea += h2v[i] * sW3[i];
    atomicAdd(&energy[img[a]], ea);

    float dz2[H_];
    #pragma unroll
    for (int i = 0; i < H_; ++i) dz2[i] = sW3[i] * (1.0f - h2v[i] * h2v[i]);
    float dz1[H_];
    #pragma unroll
    for (int i = 0; i < H_; ++i) {
        float d = 0.0f;
        #pragma unroll
        for (int j = 0; j < H_; ++j) d += sW2[i * H_ + j] * dz2[j];
        dz1[i] = d * (1.0f - h1v[i] * h1v[i]);
    }
    float* op = dEflat + (size_t)rank[a] * P_;
    #pragma unroll
    for (int p = 0; p < P_; p += 4) {
        float4 v4;
        float d0 = 0.f, d1 = 0.f, d2 = 0.f, d3 = 0.f;
        #pragma unroll
        for (int i = 0; i < H_; ++i) {
            d0 += sW1[(p    ) * H_ + i] * dz1[i];
            d1 += sW1[(p + 1) * H_ + i] * dz1[i];
            d2 += sW1[(p + 2) * H_ + i] * dz1[i];
            d3 += sW1[(p + 3) * H_ + i] * dz1[i];
        }
        v4.x = d0; v4.y = d1; v4.z = d2; v4.w = d3;
        *(float4*)(op + p) = v4;
    }
}

// ---------------- sparse force: bin nnz by row window -----------------------
// Pass A: per-block histogram over row buckets. binHist[bin*NCB + blk]
__global__ __launch_bounds__(BLK) void bin_hist_kernel(const int* __restrict__ rows,
                                                       int* __restrict__ binHist) {
    __shared__ int h[NBIN];
    const int t = threadIdx.x, b = blockIdx.x;
    for (int i = t; i < NBIN; i += BLK) h[i] = 0;
    __syncthreads();
    const int base = b * CITEMS;
    #pragma unroll 4
    for (int j = 0; j < CITEMS / BLK; ++j) {
        int k = base + j * BLK + t;
        if (k < NNZ_) atomicAdd(&h[rows[k] >> RBITS], 1);
    }
    __syncthreads();
    for (int i = t; i < NBIN; i += BLK) binHist[i * NCB + b] = h[i];
}

// Pass B1: per-bin exclusive scan across the NCB blocks; totals out.
__global__ void bin_scan_blocks_kernel(int* __restrict__ binHist, int* __restrict__ binTotal) {
    __shared__ int s[BLK];
    const int v = blockIdx.x, t = threadIdx.x;
    int carry = 0;
    for (int c = 0; c < NCB; c += BLK) {
        int idx = c + t;
        int val = (idx < NCB) ? binHist[v * NCB + idx] : 0;
        s[t] = val; __syncthreads();
        for (int off = 1; off < BLK; off <<= 1) {
            int tmp = (t >= off) ? s[t - off] : 0;
            __syncthreads();
            s[t] += tmp;
            __syncthreads();
        }
        int excl = s[t] - val;
        int tot  = s[BLK - 1];
        if (idx < NCB) binHist[v * NCB + idx] = carry + excl;
        carry += tot;
        __syncthreads();
    }
    if (t == 0) binTotal[v] = carry;
}

// Pass B2: exclusive scan of bin totals -> binBase[NBIN+1]
__global__ void bin_base_scan_kernel(const int* __restrict__ binTotal, int* __restrict__ binBase) {
    __shared__ int s[BLK];
    const int t = threadIdx.x;
    int carry = 0;
    for (int c = 0; c < NBIN; c += BLK) {
        int idx = c + t;
        int val = (idx < NBIN) ? binTotal[idx] : 0;
        s[t] = val; __syncthreads();
        for (int off = 1; off < BLK; off <<= 1) {
            int tmp = (t >= off) ? s[t - off] : 0;
            __syncthreads();
            s[t] += tmp;
            __syncthreads();
        }
        if (idx < NBIN) binBase[idx] = carry + (s[t] - val);
        carry += s[BLK - 1];
        __syncthreads();
    }
    if (t == 0) binBase[NBIN] = carry;
}

// Pass C: scatter packed items into bin order.
// item = { (localRow<<20)|col , val }  (localRow 12 bits, col 20 bits: 540000 < 2^20)
__global__ __launch_bounds__(BLK) void bin_scatter_kernel(
    const int* __restrict__ rows, const int* __restrict__ cols, const float* __restrict__ vals,
    const int* __restrict__ binHist, const int* __restrict__ binBase,
    uint2* __restrict__ bm)
{
    __shared__ int cur[NBIN];
    const int t = threadIdx.x, b = blockIdx.x;
    for (int i = t; i < NBIN; i += BLK) cur[i] = binBase[i] + binHist[i * NCB + b];
    __syncthreads();
    const int base = b * CITEMS;
    #pragma unroll 4
    for (int j = 0; j < CITEMS / BLK; ++j) {
        int k = base + j * BLK + t;
        if (k < NNZ_) {
            int r = rows[k];
            int c = cols[k];
            float v = vals[k];
            int bin = r >> RBITS;
            int idx = atomicAdd(&cur[bin], 1);
            bm[idx] = make_uint2((unsigned)(((r & (RWIN - 1)) << 20) | c),
                                 __float_as_uint(v));
        }
    }
}

// Pass D: per bin, stage dEflat window in LDS, gather + atomic scatter.
__global__ __launch_bounds__(BLK) void bin_force_kernel(
    const uint2* __restrict__ bm, const int* __restrict__ binBase,
    const float* __restrict__ dEflat, float* __restrict__ force)
{
    __shared__ float w[RWIN];
    const int t = threadIdx.x, bin = blockIdx.x;
    const int rbase = bin << RBITS;
    const int n = min(RWIN, P_ * QTOT - rbase);   // last window = 3328 (mult of 4)
    for (int i = t * 4; i < n; i += BLK * 4) {
        float4 v4 = *(const float4*)(dEflat + rbase + i);
        w[i] = v4.x; w[i + 1] = v4.y; w[i + 2] = v4.z; w[i + 3] = v4.w;
    }
    __syncthreads();
    const int start = binBase[bin];
    const int cnt   = binBase[bin + 1] - start;
    for (int i = t; i < cnt; i += BLK) {
        uint2 u = bm[start + i];
        float c = -__uint_as_float(u.y) * w[u.x >> 20];
        atomicAdd(&force[u.x & 0xFFFFF], c);
    }
}

// ---------------- fallback (small ws): direct COO scatter -------------------
__global__ void force_kernel(const int* __restrict__ rows, const int* __restrict__ cols,
                             const float* __restrict__ vals, const float* __restrict__ dEflat,
                             float* __restrict__ force) {
    int k = blockIdx.x * blockDim.x + threadIdx.x;
    if (k < NNZ_) {
        float contrib = -vals[k] * dEflat[rows[k]];
        atomicAdd(&force[cols[k]], contrib);
    }
}

extern "C" void kernel_launch(void* const* d_in, const int* in_sizes, int n_in,
                              void* d_out, int out_size, void* d_ws, size_t ws_size,
                              hipStream_t stream) {
    (void)in_sizes; (void)n_in; (void)out_size;
    const float* fps  = (const float*)d_in[0];
    const float* W1   = (const float*)d_in[1];
    const float* b1   = (const float*)d_in[2];
    const float* W2   = (const float*)d_in[3];
    const float* b2   = (const float*)d_in[4];
    const float* W3   = (const float*)d_in[5];
    const float* b3   = (const float*)d_in[6];
    const int*   img  = (const int*)d_in[7];
    const int*   rows = (const int*)d_in[8];
    const int*   cols = (const int*)d_in[9];
    const float* vals = (const float*)d_in[10];

    char* ws = (char*)d_ws;
    // rank pipeline scratch
    int*   g_hist  = (int*)(ws);                     //  5,068,800 B
    int*   g_total = (int*)(ws + 5068800);           //      7,200 B
    int*   g_base  = (int*)(ws + 5076000);           //      7,200 B
    int*   rank    = (int*)(ws + 5083200);           //    720,000 B
    float* dEflat  = (float*)(ws + 5803200);         // 28,800,000 B
    // bin pipeline scratch
    int*   binHist  = (int*)(ws + 34603200);         //  6,181,128 B (NBIN*NCB*4)
    int*   binTotal = (int*)(ws + 40784336);         //      7,032 B
    int*   binBase  = (int*)(ws + 40791376);         //      7,036 B
    uint2* bm       = (uint2*)(ws + 40798416);       // 115,200,000 B
    const size_t WS_NEEDED = 155998416;

    float* energy = (float*)d_out;                   // [1800]
    float* force  = (float*)d_out + NIMG_;           // [540000]

    const int nOut = NIMG_ + 3 * QTOT;
    zero_kernel<<<(nOut + BLK - 1) / BLK, BLK, 0, stream>>>((float*)d_out, nOut);

    // atom rank (stable argsort of image_idx)
    hist_kernel<<<NB, BLK, 0, stream>>>(img, g_hist);
    scan_blocks_kernel<<<NIMG_, BLK, 0, stream>>>(g_hist, g_total);
    scan_buckets_kernel<<<1, BLK, 0, stream>>>(g_total, g_base);
    rank_kernel<<<NB, BLK, 0, stream>>>(img, g_hist, g_base, rank);

    // per-atom MLP fwd+bwd, energies + ordered jacobian rows
    dim3 gm((QE_ + BLK - 1) / BLK, E_);
    mlp_kernel<<<gm, BLK, 0, stream>>>(fps, W1, b1, W2, b2, W3, b3, img, rank,
                                       energy, dEflat);

    if (ws_size >= WS_NEEDED) {
        // row-binned sparse force
        bin_hist_kernel<<<NCB, BLK, 0, stream>>>(rows, binHist);
        bin_scan_blocks_kernel<<<NBIN, BLK, 0, stream>>>(binHist, binTotal);
        bin_base_scan_kernel<<<1, BLK, 0, stream>>>(binTotal, binBase);
        bin_scatter_kernel<<<NCB, BLK, 0, stream>>>(rows, cols, vals, binHist, binBase, bm);
        bin_force_kernel<<<NBIN, BLK, 0, stream>>>(bm, binBase, dEflat, force);
    } else {
        force_kernel<<<NNZ_ / BLK, BLK, 0, stream>>>(rows, cols, vals, dEflat, force);
    }
}

// Round 3
// 914.321 us; speedup vs baseline: 1.5349x; 1.5349x over previous
//
#include <hip/hip_runtime.h>
#include <math.h>

#define E_    3
#define QE_   60000
#define QTOT  180000      // E_*QE_
#define P_    40
#define H_    20
#define NIMG_ 1800
#define NNZ_  14400000
#define BLK   256
#define NB    704         // ceil(QTOT/BLK)

// column-window binning for the sparse force scatter
#define CW_BITS 9
#define CW      512                   // cols per window (2 KB LDS accumulator)
#define NCOLB   1055                  // ceil(3*QTOT / CW)
#define CI2     65536                 // nnz items per binning block
#define NCB2    220                   // ceil(NNZ_/CI2)

// ---------------- zero init (d_out is poisoned 0xAA every launch) -----------
__global__ void zero_kernel(float* __restrict__ out, int n) {
    int i = blockIdx.x * blockDim.x + threadIdx.x;
    if (i < n) out[i] = 0.0f;
}

// ---------------- stable counting sort for atom ranks ----------------------
// g_hist layout: bucket-major g_hist[v*NB + b]
__global__ void hist_kernel(const int* __restrict__ img, int* __restrict__ g_hist) {
    __shared__ int h[NIMG_];
    const int t = threadIdx.x, b = blockIdx.x;
    for (int v = t; v < NIMG_; v += BLK) h[v] = 0;
    __syncthreads();
    int a = b * BLK + t;
    if (a < QTOT) atomicAdd(&h[img[a]], 1);
    __syncthreads();
    for (int v = t; v < NIMG_; v += BLK) g_hist[v * NB + b] = h[v];
}

__global__ void scan_blocks_kernel(int* __restrict__ g_hist, int* __restrict__ g_total) {
    __shared__ int s[BLK];
    const int v = blockIdx.x, t = threadIdx.x;
    int carry = 0;
    for (int c = 0; c < NB; c += BLK) {
        int idx = c + t;
        int val = (idx < NB) ? g_hist[v * NB + idx] : 0;
        s[t] = val; __syncthreads();
        for (int off = 1; off < BLK; off <<= 1) {
            int tmp = (t >= off) ? s[t - off] : 0;
            __syncthreads();
            s[t] += tmp;
            __syncthreads();
        }
        int excl = s[t] - val;
        int tot  = s[BLK - 1];
        if (idx < NB) g_hist[v * NB + idx] = carry + excl;
        carry += tot;
        __syncthreads();
    }
    if (t == 0) g_total[v] = carry;
}

__global__ void scan_buckets_kernel(const int* __restrict__ g_total, int* __restrict__ g_base) {
    __shared__ int s[BLK];
    const int t = threadIdx.x;
    int carry = 0;
    for (int c = 0; c < NIMG_; c += BLK) {
        int idx = c + t;
        int val = (idx < NIMG_) ? g_total[idx] : 0;
        s[t] = val; __syncthreads();
        for (int off = 1; off < BLK; off <<= 1) {
            int tmp = (t >= off) ? s[t - off] : 0;
            __syncthreads();
            s[t] += tmp;
            __syncthreads();
        }
        if (idx < NIMG_) g_base[idx] = carry + (s[t] - val);
        carry += s[BLK - 1];
        __syncthreads();
    }
}

__global__ void rank_kernel(const int* __restrict__ img, const int* __restrict__ g_hist,
                            const int* __restrict__ g_base, int* __restrict__ rank) {
    __shared__ int simg[BLK];
    const int t = threadIdx.x, b = blockIdx.x;
    int a = b * BLK + t;
    int v = (a < QTOT) ? img[a] : -1;
    simg[t] = v;
    __syncthreads();
    if (a < QTOT) {
        int local = 0;
        for (int j = 0; j < t; ++j) {
            if (simg[j] == v) local++;
        }
        rank[a] = g_base[v] + g_hist[v * NB + b] + local;
    }
}

// ---------------- per-atom MLP forward + backward ---------------------------
__global__ __launch_bounds__(BLK) void mlp_kernel(
    const float* __restrict__ fps, const float* __restrict__ W1, const float* __restrict__ b1,
    const float* __restrict__ W2, const float* __restrict__ b2, const float* __restrict__ W3,
    const float* __restrict__ b3, const int* __restrict__ img, const int* __restrict__ rank,
    float* __restrict__ energy, float* __restrict__ dEflat)
{
    __shared__ float sW1[P_ * H_], sW2[H_ * H_], sW3[H_], sB1[H_], sB2[H_];
    __shared__ float sB3;
    const int e = blockIdx.y;
    const int t = threadIdx.x;
    for (int i = t; i < P_ * H_; i += BLK) sW1[i] = W1[e * P_ * H_ + i];
    for (int i = t; i < H_ * H_; i += BLK) sW2[i] = W2[e * H_ * H_ + i];
    if (t < H_) { sW3[t] = W3[e * H_ + t]; sB1[t] = b1[e * H_ + t]; sB2[t] = b2[e * H_ + t]; }
    if (t == 0) sB3 = b3[e];
    __syncthreads();

    int q = blockIdx.x * BLK + t;
    if (q >= QE_) return;
    int a = e * QE_ + q;

    const float* xp = fps + (size_t)a * P_;
    float x[P_];
    #pragma unroll
    for (int p = 0; p < P_; p += 4) {
        float4 v4 = *(const float4*)(xp + p);
        x[p] = v4.x; x[p+1] = v4.y; x[p+2] = v4.z; x[p+3] = v4.w;
    }

    float h1v[H_], h2v[H_];
    #pragma unroll
    for (int i = 0; i < H_; ++i) {
        float z = sB1[i];
        #pragma unroll
        for (int p = 0; p < P_; ++p) z += x[p] * sW1[p * H_ + i];
        h1v[i] = tanhf(z);
    }
    #pragma unroll
    for (int i = 0; i < H_; ++i) {
        float z = sB2[i];
        #pragma unroll
        for (int j = 0; j < H_; ++j) z += h1v[j] * sW2[j * H_ + i];
        h2v[i] = tanhf(z);
    }
    float ea = sB3;
    #pragma unroll
    for (int i = 0; i < H_; ++i) ea += h2v[i] * sW3[i];
    atomicAdd(&energy[img[a]], ea);

    float dz2[H_];
    #pragma unroll
    for (int i = 0; i < H_; ++i) dz2[i] = sW3[i] * (1.0f - h2v[i] * h2v[i]);
    float dz1[H_];
    #pragma unroll
    for (int i = 0; i < H_; ++i) {
        float d = 0.0f;
        #pragma unroll
        for (int j = 0; j < H_; ++j) d += sW2[i * H_ + j] * dz2[j];
        dz1[i] = d * (1.0f - h1v[i] * h1v[i]);
    }
    float* op = dEflat + (size_t)rank[a] * P_;
    #pragma unroll
    for (int p = 0; p < P_; p += 4) {
        float4 v4;
        float d0 = 0.f, d1 = 0.f, d2 = 0.f, d3 = 0.f;
        #pragma unroll
        for (int i = 0; i < H_; ++i) {
            d0 += sW1[(p    ) * H_ + i] * dz1[i];
            d1 += sW1[(p + 1) * H_ + i] * dz1[i];
            d2 += sW1[(p + 2) * H_ + i] * dz1[i];
            d3 += sW1[(p + 3) * H_ + i] * dz1[i];
        }
        v4.x = d0; v4.y = d1; v4.z = d2; v4.w = d3;
        *(float4*)(op + p) = v4;
    }
}

// ---------------- sparse force: counting sort by column window --------------
// Pass A: per-block histogram over col windows. colHist[bin*NCB2 + blk]
__global__ __launch_bounds__(BLK) void col_hist_kernel(const int* __restrict__ cols,
                                                       int* __restrict__ colHist) {
    __shared__ int h[NCOLB];
    const int t = threadIdx.x, b = blockIdx.x;
    for (int i = t; i < NCOLB; i += BLK) h[i] = 0;
    __syncthreads();
    const int base = b * CI2;
    #pragma unroll 4
    for (int j = 0; j < CI2 / BLK; ++j) {
        int k = base + j * BLK + t;
        if (k < NNZ_) atomicAdd(&h[cols[k] >> CW_BITS], 1);
    }
    __syncthreads();
    for (int i = t; i < NCOLB; i += BLK) colHist[i * NCB2 + b] = h[i];
}

// Pass B1: per-bin exclusive scan across the NCB2 blocks; totals out.
__global__ void col_scan_blocks_kernel(int* __restrict__ colHist, int* __restrict__ colTotal) {
    __shared__ int s[BLK];
    const int v = blockIdx.x, t = threadIdx.x;
    int carry = 0;
    for (int c = 0; c < NCB2; c += BLK) {
        int idx = c + t;
        int val = (idx < NCB2) ? colHist[v * NCB2 + idx] : 0;
        s[t] = val; __syncthreads();
        for (int off = 1; off < BLK; off <<= 1) {
            int tmp = (t >= off) ? s[t - off] : 0;
            __syncthreads();
            s[t] += tmp;
            __syncthreads();
        }
        int excl = s[t] - val;
        int tot  = s[BLK - 1];
        if (idx < NCB2) colHist[v * NCB2 + idx] = carry + excl;
        carry += tot;
        __syncthreads();
    }
    if (t == 0) colTotal[v] = carry;
}

// Pass B2: exclusive scan of bin totals -> colBase[NCOLB+1]
__global__ void col_base_scan_kernel(const int* __restrict__ colTotal, int* __restrict__ colBase) {
    __shared__ int s[BLK];
    const int t = threadIdx.x;
    int carry = 0;
    for (int c = 0; c < NCOLB; c += BLK) {
        int idx = c + t;
        int val = (idx < NCOLB) ? colTotal[idx] : 0;
        s[t] = val; __syncthreads();
        for (int off = 1; off < BLK; off <<= 1) {
            int tmp = (t >= off) ? s[t - off] : 0;
            __syncthreads();
            s[t] += tmp;
            __syncthreads();
        }
        if (idx < NCOLB) colBase[idx] = carry + (s[t] - val);
        carry += s[BLK - 1];
        __syncthreads();
    }
    if (t == 0) colBase[NCOLB] = carry;
}

// Pass C: scatter packed items into col-bin order.
// item = { (row<<9)|colLocal , val }  (row < 7.2M < 2^23, colLocal 9 bits)
__global__ __launch_bounds__(BLK) void col_scatter_kernel(
    const int* __restrict__ rows, const int* __restrict__ cols, const float* __restrict__ vals,
    const int* __restrict__ colHist, const int* __restrict__ colBase,
    uint2* __restrict__ bm2)
{
    __shared__ int cur[NCOLB];
    const int t = threadIdx.x, b = blockIdx.x;
    for (int i = t; i < NCOLB; i += BLK) cur[i] = colBase[i] + colHist[i * NCB2 + b];
    __syncthreads();
    const int base = b * CI2;
    #pragma unroll 4
    for (int j = 0; j < CI2 / BLK; ++j) {
        int k = base + j * BLK + t;
        if (k < NNZ_) {
            int r = rows[k];
            int c = cols[k];
            float v = vals[k];
            int bin = c >> CW_BITS;
            int idx = atomicAdd(&cur[bin], 1);
            bm2[idx] = make_uint2((unsigned)((r << CW_BITS) | (c & (CW - 1))),
                                  __float_as_uint(v));
        }
    }
}

// Pass D: one block per col window — gather dEflat (L2/L3-resident), LDS
// float accumulate, single coalesced write. NO global float atomics.
__global__ __launch_bounds__(BLK) void col_force_kernel(
    const uint2* __restrict__ bm2, const int* __restrict__ colBase,
    const float* __restrict__ dEflat, float* __restrict__ force)
{
    __shared__ float w[CW];
    const int t = threadIdx.x, bin = blockIdx.x;
    for (int i = t; i < CW; i += BLK) w[i] = 0.0f;
    __syncthreads();
    const int start = colBase[bin];
    const int cnt   = colBase[bin + 1] - start;
    const int end   = start + cnt;
    const int nb = (cnt + BLK * 4 - 1) / (BLK * 4);
    for (int itb = 0; itb < nb; ++itb) {
        int base = start + itb * BLK * 4 + t * 4;
        int rem = end - base;
        if (rem >= 4) {
            uint2 u0 = bm2[base], u1 = bm2[base + 1], u2 = bm2[base + 2], u3 = bm2[base + 3];
            float d0 = dEflat[u0.x >> CW_BITS];
            float d1 = dEflat[u1.x >> CW_BITS];
            float d2 = dEflat[u2.x >> CW_BITS];
            float d3 = dEflat[u3.x >> CW_BITS];
            atomicAdd(&w[u0.x & (CW - 1)], -__uint_as_float(u0.y) * d0);
            atomicAdd(&w[u1.x & (CW - 1)], -__uint_as_float(u1.y) * d1);
            atomicAdd(&w[u2.x & (CW - 1)], -__uint_as_float(u2.y) * d2);
            atomicAdd(&w[u3.x & (CW - 1)], -__uint_as_float(u3.y) * d3);
        } else if (rem > 0) {
            for (int j = 0; j < rem; ++j) {
                uint2 u = bm2[base + j];
                float d = dEflat[u.x >> CW_BITS];
                atomicAdd(&w[u.x & (CW - 1)], -__uint_as_float(u.y) * d);
            }
        }
    }
    __syncthreads();
    const int cbase = bin << CW_BITS;
    const int n = min(CW, 3 * QTOT - cbase);
    for (int i = t; i < n; i += BLK) force[cbase + i] = w[i];
}

// ---------------- fallback (small ws): direct COO scatter -------------------
__global__ void force_kernel(const int* __restrict__ rows, const int* __restrict__ cols,
                             const float* __restrict__ vals, const float* __restrict__ dEflat,
                             float* __restrict__ force) {
    int k = blockIdx.x * blockDim.x + threadIdx.x;
    if (k < NNZ_) {
        float contrib = -vals[k] * dEflat[rows[k]];
        atomicAdd(&force[cols[k]], contrib);
    }
}

extern "C" void kernel_launch(void* const* d_in, const int* in_sizes, int n_in,
                              void* d_out, int out_size, void* d_ws, size_t ws_size,
                              hipStream_t stream) {
    (void)in_sizes; (void)n_in; (void)out_size;
    const float* fps  = (const float*)d_in[0];
    const float* W1   = (const float*)d_in[1];
    const float* b1   = (const float*)d_in[2];
    const float* W2   = (const float*)d_in[3];
    const float* b2   = (const float*)d_in[4];
    const float* W3   = (const float*)d_in[5];
    const float* b3   = (const float*)d_in[6];
    const int*   img  = (const int*)d_in[7];
    const int*   rows = (const int*)d_in[8];
    const int*   cols = (const int*)d_in[9];
    const float* vals = (const float*)d_in[10];

    char* ws = (char*)d_ws;
    // rank pipeline scratch
    int*   g_hist  = (int*)(ws);                     //  5,068,800 B
    int*   g_total = (int*)(ws + 5068800);           //      7,200 B
    int*   g_base  = (int*)(ws + 5076000);           //      7,200 B
    int*   rank    = (int*)(ws + 5083200);           //    720,000 B
    float* dEflat  = (float*)(ws + 5803200);         // 28,800,000 B
    // col-bin pipeline scratch
    int*   colHist  = (int*)(ws + 34603200);         //    928,400 B (NCOLB*NCB2*4)
    int*   colTotal = (int*)(ws + 35531600);         //      4,220 B
    int*   colBase  = (int*)(ws + 35535824);         //      4,224 B
    uint2* bm2      = (uint2*)(ws + 35540048);       // 115,200,000 B
    const size_t WS_NEEDED = 150740048;

    float* energy = (float*)d_out;                   // [1800]
    float* force  = (float*)d_out + NIMG_;           // [540000]

    const int nOut = NIMG_ + 3 * QTOT;
    zero_kernel<<<(nOut + BLK - 1) / BLK, BLK, 0, stream>>>((float*)d_out, nOut);

    // atom rank (stable argsort of image_idx)
    hist_kernel<<<NB, BLK, 0, stream>>>(img, g_hist);
    scan_blocks_kernel<<<NIMG_, BLK, 0, stream>>>(g_hist, g_total);
    scan_buckets_kernel<<<1, BLK, 0, stream>>>(g_total, g_base);
    rank_kernel<<<NB, BLK, 0, stream>>>(img, g_hist, g_base, rank);

    // per-atom MLP fwd+bwd, energies + ordered jacobian rows
    dim3 gm((QE_ + BLK - 1) / BLK, E_);
    mlp_kernel<<<gm, BLK, 0, stream>>>(fps, W1, b1, W2, b2, W3, b3, img, rank,
                                       energy, dEflat);

    if (ws_size >= WS_NEEDED) {
        // counting sort by column window, then atomic-free accumulation
        col_hist_kernel<<<NCB2, BLK, 0, stream>>>(cols, colHist);
        col_scan_blocks_kernel<<<NCOLB, BLK, 0, stream>>>(colHist, colTotal);
        col_base_scan_kernel<<<1, BLK, 0, stream>>>(colTotal, colBase);
        col_scatter_kernel<<<NCB2, BLK, 0, stream>>>(rows, cols, vals, colHist, colBase, bm2);
        col_force_kernel<<<NCOLB, BLK, 0, stream>>>(bm2, colBase, dEflat, force);
    } else {
        force_kernel<<<NNZ_ / BLK, BLK, 0, stream>>>(rows, cols, vals, dEflat, force);
    }
}

// Round 4
// 661.444 us; speedup vs baseline: 2.1217x; 1.3823x over previous
//
#include <hip/hip_runtime.h>
#include <math.h>

#define E_    3
#define QE_   60000
#define QTOT  180000      // E_*QE_
#define P_    40
#define H_    20
#define NIMG_ 1800
#define NNZ_  14400000
#define BLK   256
#define NB    704         // ceil(QTOT/BLK)

// column-window partition for the sparse force scatter
#define CW_BITS 12
#define CW      4096                  // cols per window (16 KB LDS accumulator)
#define NBIN    132                   // ceil(3*QTOT / CW)
#define SUBS    8                     // sub-slices per bin in force kernel
#define SC      8192                  // nnz items per scatter/hist block
#define NSB     1758                  // ceil(NNZ_/SC)

// ---------------- zero init (d_out is poisoned 0xAA every launch) -----------
__global__ void zero_kernel(float* __restrict__ out, int n) {
    int i = blockIdx.x * blockDim.x + threadIdx.x;
    if (i < n) out[i] = 0.0f;
}

// ---------------- stable counting sort for atom ranks ----------------------
__global__ void hist_kernel(const int* __restrict__ img, int* __restrict__ g_hist) {
    __shared__ int h[NIMG_];
    const int t = threadIdx.x, b = blockIdx.x;
    for (int v = t; v < NIMG_; v += BLK) h[v] = 0;
    __syncthreads();
    int a = b * BLK + t;
    if (a < QTOT) atomicAdd(&h[img[a]], 1);
    __syncthreads();
    for (int v = t; v < NIMG_; v += BLK) g_hist[v * NB + b] = h[v];
}

__global__ void scan_blocks_kernel(int* __restrict__ g_hist, int* __restrict__ g_total) {
    __shared__ int s[BLK];
    const int v = blockIdx.x, t = threadIdx.x;
    int carry = 0;
    for (int c = 0; c < NB; c += BLK) {
        int idx = c + t;
        int val = (idx < NB) ? g_hist[v * NB + idx] : 0;
        s[t] = val; __syncthreads();
        for (int off = 1; off < BLK; off <<= 1) {
            int tmp = (t >= off) ? s[t - off] : 0;
            __syncthreads();
            s[t] += tmp;
            __syncthreads();
        }
        int excl = s[t] - val;
        int tot  = s[BLK - 1];
        if (idx < NB) g_hist[v * NB + idx] = carry + excl;
        carry += tot;
        __syncthreads();
    }
    if (t == 0) g_total[v] = carry;
}

__global__ void scan_buckets_kernel(const int* __restrict__ g_total, int* __restrict__ g_base) {
    __shared__ int s[BLK];
    const int t = threadIdx.x;
    int carry = 0;
    for (int c = 0; c < NIMG_; c += BLK) {
        int idx = c + t;
        int val = (idx < NIMG_) ? g_total[idx] : 0;
        s[t] = val; __syncthreads();
        for (int off = 1; off < BLK; off <<= 1) {
            int tmp = (t >= off) ? s[t - off] : 0;
            __syncthreads();
            s[t] += tmp;
            __syncthreads();
        }
        if (idx < NIMG_) g_base[idx] = carry + (s[t] - val);
        carry += s[BLK - 1];
        __syncthreads();
    }
}

__global__ void rank_kernel(const int* __restrict__ img, const int* __restrict__ g_hist,
                            const int* __restrict__ g_base, int* __restrict__ rank) {
    __shared__ int simg[BLK];
    const int t = threadIdx.x, b = blockIdx.x;
    int a = b * BLK + t;
    int v = (a < QTOT) ? img[a] : -1;
    simg[t] = v;
    __syncthreads();
    if (a < QTOT) {
        int local = 0;
        for (int j = 0; j < t; ++j) {
            if (simg[j] == v) local++;
        }
        rank[a] = g_base[v] + g_hist[v * NB + b] + local;
    }
}

// ---------------- per-atom MLP forward + backward ---------------------------
__global__ __launch_bounds__(BLK) void mlp_kernel(
    const float* __restrict__ fps, const float* __restrict__ W1, const float* __restrict__ b1,
    const float* __restrict__ W2, const float* __restrict__ b2, const float* __restrict__ W3,
    const float* __restrict__ b3, const int* __restrict__ img, const int* __restrict__ rank,
    float* __restrict__ energy, float* __restrict__ dEflat)
{
    __shared__ float sW1[P_ * H_], sW2[H_ * H_], sW3[H_], sB1[H_], sB2[H_];
    __shared__ float sB3;
    const int e = blockIdx.y;
    const int t = threadIdx.x;
    for (int i = t; i < P_ * H_; i += BLK) sW1[i] = W1[e * P_ * H_ + i];
    for (int i = t; i < H_ * H_; i += BLK) sW2[i] = W2[e * H_ * H_ + i];
    if (t < H_) { sW3[t] = W3[e * H_ + t]; sB1[t] = b1[e * H_ + t]; sB2[t] = b2[e * H_ + t]; }
    if (t == 0) sB3 = b3[e];
    __syncthreads();

    int q = blockIdx.x * BLK + t;
    if (q >= QE_) return;
    int a = e * QE_ + q;

    const float* xp = fps + (size_t)a * P_;
    float x[P_];
    #pragma unroll
    for (int p = 0; p < P_; p += 4) {
        float4 v4 = *(const float4*)(xp + p);
        x[p] = v4.x; x[p+1] = v4.y; x[p+2] = v4.z; x[p+3] = v4.w;
    }

    float h1v[H_], h2v[H_];
    #pragma unroll
    for (int i = 0; i < H_; ++i) {
        float z = sB1[i];
        #pragma unroll
        for (int p = 0; p < P_; ++p) z += x[p] * sW1[p * H_ + i];
        h1v[i] = tanhf(z);
    }
    #pragma unroll
    for (int i = 0; i < H_; ++i) {
        float z = sB2[i];
        #pragma unroll
        for (int j = 0; j < H_; ++j) z += h1v[j] * sW2[j * H_ + i];
        h2v[i] = tanhf(z);
    }
    float ea = sB3;
    #pragma unroll
    for (int i = 0; i < H_; ++i) ea += h2v[i] * sW3[i];
    atomicAdd(&energy[img[a]], ea);

    float dz2[H_];
    #pragma unroll
    for (int i = 0; i < H_; ++i) dz2[i] = sW3[i] * (1.0f - h2v[i] * h2v[i]);
    float dz1[H_];
    #pragma unroll
    for (int i = 0; i < H_; ++i) {
        float d = 0.0f;
        #pragma unroll
        for (int j = 0; j < H_; ++j) d += sW2[i * H_ + j] * dz2[j];
        dz1[i] = d * (1.0f - h1v[i] * h1v[i]);
    }
    float* op = dEflat + (size_t)rank[a] * P_;
    #pragma unroll
    for (int p = 0; p < P_; p += 4) {
        float4 v4;
        float d0 = 0.f, d1 = 0.f, d2 = 0.f, d3 = 0.f;
        #pragma unroll
        for (int i = 0; i < H_; ++i) {
            d0 += sW1[(p    ) * H_ + i] * dz1[i];
            d1 += sW1[(p + 1) * H_ + i] * dz1[i];
            d2 += sW1[(p + 2) * H_ + i] * dz1[i];
            d3 += sW1[(p + 3) * H_ + i] * dz1[i];
        }
        v4.x = d0; v4.y = d1; v4.z = d2; v4.w = d3;
        *(float4*)(op + p) = v4;
    }
}

// ---------------- sparse force pipeline (132 col windows of 4096) -----------
// Pass A: per-block histogram. binHist[bin*NSB + blk]
__global__ __launch_bounds__(BLK) void fhist_kernel(const int* __restrict__ cols,
                                                    int* __restrict__ binHist) {
    __shared__ int h[NBIN];
    const int t = threadIdx.x, b = blockIdx.x;
    if (t < NBIN) h[t] = 0;
    __syncthreads();
    const int base = b * SC;
    if (base + SC <= NNZ_) {
        const int4* c4 = (const int4*)(cols + base);
        #pragma unroll
        for (int j = 0; j < SC / (BLK * 4); ++j) {
            int4 cc = c4[j * BLK + t];
            atomicAdd(&h[cc.x >> CW_BITS], 1);
            atomicAdd(&h[cc.y >> CW_BITS], 1);
            atomicAdd(&h[cc.z >> CW_BITS], 1);
            atomicAdd(&h[cc.w >> CW_BITS], 1);
        }
    } else {
        for (int j = 0; j < SC / BLK; ++j) {
            int k = base + j * BLK + t;
            if (k < NNZ_) atomicAdd(&h[cols[k] >> CW_BITS], 1);
        }
    }
    __syncthreads();
    if (t < NBIN) binHist[t * NSB + b] = h[t];
}

// Pass B1: per-bin exclusive scan across the NSB blocks; totals out.
__global__ void fscan_blocks_kernel(int* __restrict__ binHist, int* __restrict__ binTotal) {
    __shared__ int s[BLK];
    const int v = blockIdx.x, t = threadIdx.x;
    int carry = 0;
    for (int c = 0; c < NSB; c += BLK) {
        int idx = c + t;
        int val = (idx < NSB) ? binHist[v * NSB + idx] : 0;
        s[t] = val; __syncthreads();
        for (int off = 1; off < BLK; off <<= 1) {
            int tmp = (t >= off) ? s[t - off] : 0;
            __syncthreads();
            s[t] += tmp;
            __syncthreads();
        }
        int excl = s[t] - val;
        int tot  = s[BLK - 1];
        if (idx < NSB) binHist[v * NSB + idx] = carry + excl;
        carry += tot;
        __syncthreads();
    }
    if (t == 0) binTotal[v] = carry;
}

// Pass B2: exclusive scan of 132 bin totals -> binBase[NBIN+1]
__global__ void fbase_kernel(const int* __restrict__ binTotal, int* __restrict__ binBase) {
    __shared__ int s[BLK];
    const int t = threadIdx.x;
    int v = (t < NBIN) ? binTotal[t] : 0;
    s[t] = v; __syncthreads();
    for (int off = 1; off < BLK; off <<= 1) {
        int tmp = (t >= off) ? s[t - off] : 0;
        __syncthreads();
        s[t] += tmp;
        __syncthreads();
    }
    if (t < NBIN) binBase[t] = s[t] - v;
    if (t == 0) binBase[NBIN] = s[BLK - 1];
}

// Pass C: block-local counting sort + fused multiply, coalesced write-out.
// item (4 B) = (colLocal:12 << 20) | (round-to-nearest top-20 bits of fp32 contrib)
__global__ __launch_bounds__(BLK) void fscatter_kernel(
    const int* __restrict__ rows, const int* __restrict__ cols, const float* __restrict__ vals,
    const float* __restrict__ dEflat, const int* __restrict__ binHist,
    const int* __restrict__ binBase, unsigned* __restrict__ bm)
{
    __shared__ unsigned items[SC];            // 32 KB
    __shared__ unsigned char bins[SC];        //  8 KB
    __shared__ int hist[NBIN];
    __shared__ int cursor[NBIN];
    __shared__ int delta[NBIN];
    __shared__ int s[BLK];
    const int t = threadIdx.x, b = blockIdx.x;
    const int base = b * SC;
    const int nIt = min(SC, NNZ_ - base);
    const bool full = (base + SC <= NNZ_);

    if (t < NBIN) hist[t] = 0;
    __syncthreads();

    // local histogram
    if (full) {
        const int4* c4 = (const int4*)(cols + base);
        #pragma unroll
        for (int j = 0; j < SC / (BLK * 4); ++j) {
            int4 cc = c4[j * BLK + t];
            atomicAdd(&hist[cc.x >> CW_BITS], 1);
            atomicAdd(&hist[cc.y >> CW_BITS], 1);
            atomicAdd(&hist[cc.z >> CW_BITS], 1);
            atomicAdd(&hist[cc.w >> CW_BITS], 1);
        }
    } else {
        for (int j = 0; j < SC / BLK; ++j) {
            int k = base + j * BLK + t;
            if (k < NNZ_) atomicAdd(&hist[cols[k] >> CW_BITS], 1);
        }
    }
    __syncthreads();

    // local scan -> cursor (local bin start) and delta (global dst offset)
    {
        int v = (t < NBIN) ? hist[t] : 0;
        s[t] = v; __syncthreads();
        for (int off = 1; off < BLK; off <<= 1) {
            int tmp = (t >= off) ? s[t - off] : 0;
            __syncthreads();
            s[t] += tmp;
            __syncthreads();
        }
        if (t < NBIN) {
            int ls = s[t] - v;
            cursor[t] = ls;
            delta[t]  = binBase[t] + binHist[t * NSB + b] - ls;
        }
    }
    __syncthreads();

    // fused multiply + local placement (order within bin irrelevant)
    if (full) {
        const int4*   c4 = (const int4*)(cols + base);
        const int4*   r4 = (const int4*)(rows + base);
        const float4* v4 = (const float4*)(vals + base);
        #pragma unroll 2
        for (int j = 0; j < SC / (BLK * 4); ++j) {
            int idx = j * BLK + t;
            int4 cc = c4[idx];
            int4 rr = r4[idx];
            float4 vv = v4[idx];
            float d0 = dEflat[rr.x];
            float d1 = dEflat[rr.y];
            float d2 = dEflat[rr.z];
            float d3 = dEflat[rr.w];
            #define PLACE(CI, VI, DI)                                              \
            {                                                                      \
                int bin = (CI) >> CW_BITS;                                         \
                unsigned u = __float_as_uint(-(VI) * (DI));                        \
                unsigned pk = ((unsigned)((CI) & (CW - 1)) << 20)                  \
                            | ((u + 0x800u) >> 12);                                \
                int pos = atomicAdd(&cursor[bin], 1);                              \
                items[pos] = pk;                                                   \
                bins[pos] = (unsigned char)bin;                                    \
            }
            PLACE(cc.x, vv.x, d0)
            PLACE(cc.y, vv.y, d1)
            PLACE(cc.z, vv.z, d2)
            PLACE(cc.w, vv.w, d3)
        }
    } else {
        for (int j = 0; j < SC / BLK; ++j) {
            int k = base + j * BLK + t;
            if (k < NNZ_) {
                int c = cols[k];
                float d = dEflat[rows[k]];
                float v = vals[k];
                PLACE(c, v, d)
            }
        }
    }
    __syncthreads();

    // coalesced write-out in sorted order: consecutive i -> consecutive dst
    for (int i = t; i < nIt; i += BLK) {
        bm[delta[bins[i]] + i] = items[i];
    }
}

// Pass D: per (bin, sub-slice) LDS accumulation, no gather, no global atomics.
__global__ __launch_bounds__(BLK) void fforce_kernel(
    const unsigned* __restrict__ bm, const int* __restrict__ binBase,
    float* __restrict__ partial)
{
    __shared__ float w[CW];
    const int t = threadIdx.x;
    const int bin = blockIdx.x >> 3;
    const int sub = blockIdx.x & (SUBS - 1);
    for (int i = t; i < CW; i += BLK) w[i] = 0.0f;
    __syncthreads();
    const int start = binBase[bin];
    const int cnt   = binBase[bin + 1] - start;
    const int sBeg  = start + (cnt * sub) / SUBS;
    const int sEnd  = start + (cnt * (sub + 1)) / SUBS;
    int i = sBeg + t;
    for (; i + 3 * BLK < sEnd; i += 4 * BLK) {
        unsigned p0 = bm[i];
        unsigned p1 = bm[i + BLK];
        unsigned p2 = bm[i + 2 * BLK];
        unsigned p3 = bm[i + 3 * BLK];
        atomicAdd(&w[p0 >> 20], __uint_as_float((p0 & 0xFFFFFu) << 12));
        atomicAdd(&w[p1 >> 20], __uint_as_float((p1 & 0xFFFFFu) << 12));
        atomicAdd(&w[p2 >> 20], __uint_as_float((p2 & 0xFFFFFu) << 12));
        atomicAdd(&w[p3 >> 20], __uint_as_float((p3 & 0xFFFFFu) << 12));
    }
    for (; i < sEnd; i += BLK) {
        unsigned p = bm[i];
        atomicAdd(&w[p >> 20], __uint_as_float((p & 0xFFFFFu) << 12));
    }
    __syncthreads();
    float* dst = partial + (size_t)blockIdx.x * CW;
    for (int k = t; k < CW; k += BLK) dst[k] = w[k];
}

// Pass E: sum the SUBS partial windows per bin into force.
__global__ void freduce_kernel(const float* __restrict__ partial, float* __restrict__ force) {
    int i = blockIdx.x * BLK + threadIdx.x;
    if (i < 3 * QTOT) {
        int bin = i >> CW_BITS, local = i & (CW - 1);
        const float* p = partial + (size_t)bin * (CW * SUBS) + local;
        float sum = 0.0f;
        #pragma unroll
        for (int k = 0; k < SUBS; ++k) sum += p[k * CW];
        force[i] = sum;
    }
}

// ---------------- fallback (small ws): direct COO scatter -------------------
__global__ void force_kernel(const int* __restrict__ rows, const int* __restrict__ cols,
                             const float* __restrict__ vals, const float* __restrict__ dEflat,
                             float* __restrict__ force) {
    int k = blockIdx.x * blockDim.x + threadIdx.x;
    if (k < NNZ_) {
        float contrib = -vals[k] * dEflat[rows[k]];
        atomicAdd(&force[cols[k]], contrib);
    }
}

extern "C" void kernel_launch(void* const* d_in, const int* in_sizes, int n_in,
                              void* d_out, int out_size, void* d_ws, size_t ws_size,
                              hipStream_t stream) {
    (void)in_sizes; (void)n_in; (void)out_size;
    const float* fps  = (const float*)d_in[0];
    const float* W1   = (const float*)d_in[1];
    const float* b1   = (const float*)d_in[2];
    const float* W2   = (const float*)d_in[3];
    const float* b2   = (const float*)d_in[4];
    const float* W3   = (const float*)d_in[5];
    const float* b3   = (const float*)d_in[6];
    const int*   img  = (const int*)d_in[7];
    const int*   rows = (const int*)d_in[8];
    const int*   cols = (const int*)d_in[9];
    const float* vals = (const float*)d_in[10];

    char* ws = (char*)d_ws;
    // rank pipeline scratch
    int*   g_hist  = (int*)(ws);                     //  5,068,800 B
    int*   g_total = (int*)(ws + 5068800);           //      7,200 B
    int*   g_base  = (int*)(ws + 5076000);           //      7,200 B
    int*   rank    = (int*)(ws + 5083200);           //    720,000 B
    float* dEflat  = (float*)(ws + 5803200);         // 28,800,000 B
    // force pipeline scratch
    int*      binHist  = (int*)(ws + 34603200);      //    928,224 B (NBIN*NSB*4)
    int*      binTotal = (int*)(ws + 35531424);      //        528 B
    int*      binBase  = (int*)(ws + 35531952);      //        532 B (+pad)
    unsigned* bm       = (unsigned*)(ws + 35532496); // 57,600,000 B
    float*    partial  = (float*)(ws + 93132496);    // 17,301,504 B
    const size_t WS_NEEDED = 110434000;

    float* energy = (float*)d_out;                   // [1800]
    float* force  = (float*)d_out + NIMG_;           // [540000]

    const int nOut = NIMG_ + 3 * QTOT;
    zero_kernel<<<(nOut + BLK - 1) / BLK, BLK, 0, stream>>>((float*)d_out, nOut);

    // atom rank (stable argsort of image_idx)
    hist_kernel<<<NB, BLK, 0, stream>>>(img, g_hist);
    scan_blocks_kernel<<<NIMG_, BLK, 0, stream>>>(g_hist, g_total);
    scan_buckets_kernel<<<1, BLK, 0, stream>>>(g_total, g_base);
    rank_kernel<<<NB, BLK, 0, stream>>>(img, g_hist, g_base, rank);

    // per-atom MLP fwd+bwd, energies + ordered jacobian rows
    dim3 gm((QE_ + BLK - 1) / BLK, E_);
    mlp_kernel<<<gm, BLK, 0, stream>>>(fps, W1, b1, W2, b2, W3, b3, img, rank,
                                       energy, dEflat);

    if (ws_size >= WS_NEEDED) {
        fhist_kernel<<<NSB, BLK, 0, stream>>>(cols, binHist);
        fscan_blocks_kernel<<<NBIN, BLK, 0, stream>>>(binHist, binTotal);
        fbase_kernel<<<1, BLK, 0, stream>>>(binTotal, binBase);
        fscatter_kernel<<<NSB, BLK, 0, stream>>>(rows, cols, vals, dEflat,
                                                 binHist, binBase, bm);
        fforce_kernel<<<NBIN * SUBS, BLK, 0, stream>>>(bm, binBase, partial);
        freduce_kernel<<<(3 * QTOT + BLK - 1) / BLK, BLK, 0, stream>>>(partial, force);
    } else {
        force_kernel<<<NNZ_ / BLK, BLK, 0, stream>>>(rows, cols, vals, dEflat, force);
    }
}

// Round 5
// 647.695 us; speedup vs baseline: 2.1668x; 1.0212x over previous
//
#include <hip/hip_runtime.h>
#include <math.h>

#define E_    3
#define QE_   60000
#define QTOT  180000      // E_*QE_
#define P_    40
#define H_    20
#define NIMG_ 1800
#define NNZ_  14400000
#define BLK   256
#define NB    704         // ceil(QTOT/BLK)

// column-window partition for the sparse force scatter
#define CW_BITS 12
#define CW      4096                  // cols per window (16 KB LDS accumulator)
#define NBIN    132                   // ceil(3*QTOT / CW)
#define SUBS    8                     // sub-slices per bin in force kernel
#define SC      8192                  // nnz items per scatter/hist block
#define NSB     1758                  // ceil(NNZ_/SC)

typedef int   vi4 __attribute__((ext_vector_type(4)));
typedef float vf4 __attribute__((ext_vector_type(4)));

// ---------------- zero init (d_out is poisoned 0xAA every launch) -----------
__global__ void zero_kernel(float* __restrict__ out, int n) {
    int i = blockIdx.x * blockDim.x + threadIdx.x;
    if (i < n) out[i] = 0.0f;
}

// ---------------- stable counting sort for atom ranks ----------------------
__global__ void hist_kernel(const int* __restrict__ img, int* __restrict__ g_hist) {
    __shared__ int h[NIMG_];
    const int t = threadIdx.x, b = blockIdx.x;
    for (int v = t; v < NIMG_; v += BLK) h[v] = 0;
    __syncthreads();
    int a = b * BLK + t;
    if (a < QTOT) atomicAdd(&h[img[a]], 1);
    __syncthreads();
    for (int v = t; v < NIMG_; v += BLK) g_hist[v * NB + b] = h[v];
}

__global__ void scan_blocks_kernel(int* __restrict__ g_hist, int* __restrict__ g_total) {
    __shared__ int s[BLK];
    const int v = blockIdx.x, t = threadIdx.x;
    int carry = 0;
    for (int c = 0; c < NB; c += BLK) {
        int idx = c + t;
        int val = (idx < NB) ? g_hist[v * NB + idx] : 0;
        s[t] = val; __syncthreads();
        for (int off = 1; off < BLK; off <<= 1) {
            int tmp = (t >= off) ? s[t - off] : 0;
            __syncthreads();
            s[t] += tmp;
            __syncthreads();
        }
        int excl = s[t] - val;
        int tot  = s[BLK - 1];
        if (idx < NB) g_hist[v * NB + idx] = carry + excl;
        carry += tot;
        __syncthreads();
    }
    if (t == 0) g_total[v] = carry;
}

__global__ void scan_buckets_kernel(const int* __restrict__ g_total, int* __restrict__ g_base) {
    __shared__ int s[BLK];
    const int t = threadIdx.x;
    int carry = 0;
    for (int c = 0; c < NIMG_; c += BLK) {
        int idx = c + t;
        int val = (idx < NIMG_) ? g_total[idx] : 0;
        s[t] = val; __syncthreads();
        for (int off = 1; off < BLK; off <<= 1) {
            int tmp = (t >= off) ? s[t - off] : 0;
            __syncthreads();
            s[t] += tmp;
            __syncthreads();
        }
        if (idx < NIMG_) g_base[idx] = carry + (s[t] - val);
        carry += s[BLK - 1];
        __syncthreads();
    }
}

__global__ void rank_kernel(const int* __restrict__ img, const int* __restrict__ g_hist,
                            const int* __restrict__ g_base, int* __restrict__ rank) {
    __shared__ int simg[BLK];
    const int t = threadIdx.x, b = blockIdx.x;
    int a = b * BLK + t;
    int v = (a < QTOT) ? img[a] : -1;
    simg[t] = v;
    __syncthreads();
    if (a < QTOT) {
        int local = 0;
        for (int j = 0; j < t; ++j) {
            if (simg[j] == v) local++;
        }
        rank[a] = g_base[v] + g_hist[v * NB + b] + local;
    }
}

// ---------------- per-atom MLP forward + backward ---------------------------
__global__ __launch_bounds__(BLK) void mlp_kernel(
    const float* __restrict__ fps, const float* __restrict__ W1, const float* __restrict__ b1,
    const float* __restrict__ W2, const float* __restrict__ b2, const float* __restrict__ W3,
    const float* __restrict__ b3, const int* __restrict__ img, const int* __restrict__ rank,
    float* __restrict__ energy, float* __restrict__ dEflat)
{
    __shared__ float sW1[P_ * H_], sW2[H_ * H_], sW3[H_], sB1[H_], sB2[H_];
    __shared__ float sB3;
    const int e = blockIdx.y;
    const int t = threadIdx.x;
    for (int i = t; i < P_ * H_; i += BLK) sW1[i] = W1[e * P_ * H_ + i];
    for (int i = t; i < H_ * H_; i += BLK) sW2[i] = W2[e * H_ * H_ + i];
    if (t < H_) { sW3[t] = W3[e * H_ + t]; sB1[t] = b1[e * H_ + t]; sB2[t] = b2[e * H_ + t]; }
    if (t == 0) sB3 = b3[e];
    __syncthreads();

    int q = blockIdx.x * BLK + t;
    if (q >= QE_) return;
    int a = e * QE_ + q;

    const vf4* xp = (const vf4*)(fps + (size_t)a * P_);
    float x[P_];
    #pragma unroll
    for (int p = 0; p < P_; p += 4) {
        vf4 v4 = __builtin_nontemporal_load(xp + (p >> 2));
        x[p] = v4.x; x[p+1] = v4.y; x[p+2] = v4.z; x[p+3] = v4.w;
    }

    float h1v[H_], h2v[H_];
    #pragma unroll
    for (int i = 0; i < H_; ++i) {
        float z = sB1[i];
        #pragma unroll
        for (int p = 0; p < P_; ++p) z += x[p] * sW1[p * H_ + i];
        h1v[i] = tanhf(z);
    }
    #pragma unroll
    for (int i = 0; i < H_; ++i) {
        float z = sB2[i];
        #pragma unroll
        for (int j = 0; j < H_; ++j) z += h1v[j] * sW2[j * H_ + i];
        h2v[i] = tanhf(z);
    }
    float ea = sB3;
    #pragma unroll
    for (int i = 0; i < H_; ++i) ea += h2v[i] * sW3[i];
    atomicAdd(&energy[img[a]], ea);

    float dz2[H_];
    #pragma unroll
    for (int i = 0; i < H_; ++i) dz2[i] = sW3[i] * (1.0f - h2v[i] * h2v[i]);
    float dz1[H_];
    #pragma unroll
    for (int i = 0; i < H_; ++i) {
        float d = 0.0f;
        #pragma unroll
        for (int j = 0; j < H_; ++j) d += sW2[i * H_ + j] * dz2[j];
        dz1[i] = d * (1.0f - h1v[i] * h1v[i]);
    }
    float* op = dEflat + (size_t)rank[a] * P_;
    #pragma unroll
    for (int p = 0; p < P_; p += 4) {
        float4 v4;
        float d0 = 0.f, d1 = 0.f, d2 = 0.f, d3 = 0.f;
        #pragma unroll
        for (int i = 0; i < H_; ++i) {
            d0 += sW1[(p    ) * H_ + i] * dz1[i];
            d1 += sW1[(p + 1) * H_ + i] * dz1[i];
            d2 += sW1[(p + 2) * H_ + i] * dz1[i];
            d3 += sW1[(p + 3) * H_ + i] * dz1[i];
        }
        v4.x = d0; v4.y = d1; v4.z = d2; v4.w = d3;
        *(float4*)(op + p) = v4;   // cacheable: re-read by fscatter gather
    }
}

// ---------------- sparse force pipeline (132 col windows of 4096) -----------
// Pass A: per-block histogram. binHist[bin*NSB + blk]
__global__ __launch_bounds__(BLK) void fhist_kernel(const int* __restrict__ cols,
                                                    int* __restrict__ binHist) {
    __shared__ int h[NBIN];
    const int t = threadIdx.x, b = blockIdx.x;
    if (t < NBIN) h[t] = 0;
    __syncthreads();
    const int base = b * SC;
    if (base + SC <= NNZ_) {
        const vi4* c4 = (const vi4*)(cols + base);
        #pragma unroll
        for (int j = 0; j < SC / (BLK * 4); ++j) {
            vi4 cc = __builtin_nontemporal_load(c4 + j * BLK + t);
            atomicAdd(&h[cc.x >> CW_BITS], 1);
            atomicAdd(&h[cc.y >> CW_BITS], 1);
            atomicAdd(&h[cc.z >> CW_BITS], 1);
            atomicAdd(&h[cc.w >> CW_BITS], 1);
        }
    } else {
        for (int j = 0; j < SC / BLK; ++j) {
            int k = base + j * BLK + t;
            if (k < NNZ_) atomicAdd(&h[cols[k] >> CW_BITS], 1);
        }
    }
    __syncthreads();
    if (t < NBIN) binHist[t * NSB + b] = h[t];
}

// Pass B1: per-bin exclusive scan across the NSB blocks; totals out.
__global__ void fscan_blocks_kernel(int* __restrict__ binHist, int* __restrict__ binTotal) {
    __shared__ int s[BLK];
    const int v = blockIdx.x, t = threadIdx.x;
    int carry = 0;
    for (int c = 0; c < NSB; c += BLK) {
        int idx = c + t;
        int val = (idx < NSB) ? binHist[v * NSB + idx] : 0;
        s[t] = val; __syncthreads();
        for (int off = 1; off < BLK; off <<= 1) {
            int tmp = (t >= off) ? s[t - off] : 0;
            __syncthreads();
            s[t] += tmp;
            __syncthreads();
        }
        int excl = s[t] - val;
        int tot  = s[BLK - 1];
        if (idx < NSB) binHist[v * NSB + idx] = carry + excl;
        carry += tot;
        __syncthreads();
    }
    if (t == 0) binTotal[v] = carry;
}

// Pass B2: exclusive scan of 132 bin totals -> binBase[NBIN+1]
__global__ void fbase_kernel(const int* __restrict__ binTotal, int* __restrict__ binBase) {
    __shared__ int s[BLK];
    const int t = threadIdx.x;
    int v = (t < NBIN) ? binTotal[t] : 0;
    s[t] = v; __syncthreads();
    for (int off = 1; off < BLK; off <<= 1) {
        int tmp = (t >= off) ? s[t - off] : 0;
        __syncthreads();
        s[t] += tmp;
        __syncthreads();
    }
    if (t < NBIN) binBase[t] = s[t] - v;
    if (t == 0) binBase[NBIN] = s[BLK - 1];
}

// Pass C: block-local counting sort + fused multiply, coalesced write-out.
// item (4 B) = (colLocal:12 << 20) | (round-to-nearest top-20 bits of fp32 contrib)
// All streams non-temporal; dEflat is the ONLY cacheable read -> lives in L3.
__global__ __launch_bounds__(BLK) void fscatter_kernel(
    const int* __restrict__ rows, const int* __restrict__ cols, const float* __restrict__ vals,
    const float* __restrict__ dEflat, const int* __restrict__ binHist,
    const int* __restrict__ binBase, unsigned* __restrict__ bm)
{
    __shared__ unsigned items[SC];            // 32 KB
    __shared__ unsigned char bins[SC];        //  8 KB
    __shared__ int hist[NBIN];
    __shared__ int cursor[NBIN];
    __shared__ int delta[NBIN];
    __shared__ int s[BLK];
    const int t = threadIdx.x, b = blockIdx.x;
    const int base = b * SC;
    const int nIt = min(SC, NNZ_ - base);
    const bool full = (base + SC <= NNZ_);

    if (t < NBIN) hist[t] = 0;
    __syncthreads();

    // local histogram
    if (full) {
        const vi4* c4 = (const vi4*)(cols + base);
        #pragma unroll
        for (int j = 0; j < SC / (BLK * 4); ++j) {
            vi4 cc = __builtin_nontemporal_load(c4 + j * BLK + t);
            atomicAdd(&hist[cc.x >> CW_BITS], 1);
            atomicAdd(&hist[cc.y >> CW_BITS], 1);
            atomicAdd(&hist[cc.z >> CW_BITS], 1);
            atomicAdd(&hist[cc.w >> CW_BITS], 1);
        }
    } else {
        for (int j = 0; j < SC / BLK; ++j) {
            int k = base + j * BLK + t;
            if (k < NNZ_) atomicAdd(&hist[cols[k] >> CW_BITS], 1);
        }
    }
    __syncthreads();

    // local scan -> cursor (local bin start) and delta (global dst offset)
    {
        int v = (t < NBIN) ? hist[t] : 0;
        s[t] = v; __syncthreads();
        for (int off = 1; off < BLK; off <<= 1) {
            int tmp = (t >= off) ? s[t - off] : 0;
            __syncthreads();
            s[t] += tmp;
            __syncthreads();
        }
        if (t < NBIN) {
            int ls = s[t] - v;
            cursor[t] = ls;
            delta[t]  = binBase[t] + binHist[t * NSB + b] - ls;
        }
    }
    __syncthreads();

    // fused multiply + local placement (order within bin irrelevant)
    if (full) {
        const vi4* c4 = (const vi4*)(cols + base);
        const vi4* r4 = (const vi4*)(rows + base);
        const vf4* v4 = (const vf4*)(vals + base);
        #pragma unroll 2
        for (int j = 0; j < SC / (BLK * 4); ++j) {
            int idx = j * BLK + t;
            vi4 cc = __builtin_nontemporal_load(c4 + idx);
            vi4 rr = __builtin_nontemporal_load(r4 + idx);
            vf4 vv = __builtin_nontemporal_load(v4 + idx);
            float d0 = dEflat[rr.x];
            float d1 = dEflat[rr.y];
            float d2 = dEflat[rr.z];
            float d3 = dEflat[rr.w];
            #define PLACE(CI, VI, DI)                                              \
            {                                                                      \
                int bin = (CI) >> CW_BITS;                                         \
                unsigned u = __float_as_uint(-(VI) * (DI));                        \
                unsigned pk = ((unsigned)((CI) & (CW - 1)) << 20)                  \
                            | ((u + 0x800u) >> 12);                                \
                int pos = atomicAdd(&cursor[bin], 1);                              \
                items[pos] = pk;                                                   \
                bins[pos] = (unsigned char)bin;                                    \
            }
            PLACE(cc.x, vv.x, d0)
            PLACE(cc.y, vv.y, d1)
            PLACE(cc.z, vv.z, d2)
            PLACE(cc.w, vv.w, d3)
        }
    } else {
        for (int j = 0; j < SC / BLK; ++j) {
            int k = base + j * BLK + t;
            if (k < NNZ_) {
                int c = cols[k];
                float d = dEflat[rows[k]];
                float v = vals[k];
                PLACE(c, v, d)
            }
        }
    }
    __syncthreads();

    // coalesced write-out in sorted order: consecutive i -> consecutive dst
    for (int i = t; i < nIt; i += BLK) {
        __builtin_nontemporal_store(items[i], &bm[delta[bins[i]] + i]);
    }
}

// Pass D: per (bin, sub-slice) LDS accumulation, no gather, no global atomics.
__global__ __launch_bounds__(BLK) void fforce_kernel(
    const unsigned* __restrict__ bm, const int* __restrict__ binBase,
    float* __restrict__ partial)
{
    __shared__ float w[CW];
    const int t = threadIdx.x;
    const int bin = blockIdx.x >> 3;
    const int sub = blockIdx.x & (SUBS - 1);
    for (int i = t; i < CW; i += BLK) w[i] = 0.0f;
    __syncthreads();
    const int start = binBase[bin];
    const int cnt   = binBase[bin + 1] - start;
    const int sBeg  = start + (cnt * sub) / SUBS;
    const int sEnd  = start + (cnt * (sub + 1)) / SUBS;
    int i = sBeg + t;
    for (; i + 3 * BLK < sEnd; i += 4 * BLK) {
        unsigned p0 = __builtin_nontemporal_load(bm + i);
        unsigned p1 = __builtin_nontemporal_load(bm + i + BLK);
        unsigned p2 = __builtin_nontemporal_load(bm + i + 2 * BLK);
        unsigned p3 = __builtin_nontemporal_load(bm + i + 3 * BLK);
        atomicAdd(&w[p0 >> 20], __uint_as_float((p0 & 0xFFFFFu) << 12));
        atomicAdd(&w[p1 >> 20], __uint_as_float((p1 & 0xFFFFFu) << 12));
        atomicAdd(&w[p2 >> 20], __uint_as_float((p2 & 0xFFFFFu) << 12));
        atomicAdd(&w[p3 >> 20], __uint_as_float((p3 & 0xFFFFFu) << 12));
    }
    for (; i < sEnd; i += BLK) {
        unsigned p = bm[i];
        atomicAdd(&w[p >> 20], __uint_as_float((p & 0xFFFFFu) << 12));
    }
    __syncthreads();
    float* dst = partial + (size_t)blockIdx.x * CW;
    for (int k = t; k < CW; k += BLK) __builtin_nontemporal_store(w[k], dst + k);
}

// Pass E: sum the SUBS partial windows per bin into force.
__global__ void freduce_kernel(const float* __restrict__ partial, float* __restrict__ force) {
    int i = blockIdx.x * BLK + threadIdx.x;
    if (i < 3 * QTOT) {
        int bin = i >> CW_BITS, local = i & (CW - 1);
        const float* p = partial + (size_t)bin * (CW * SUBS) + local;
        float sum = 0.0f;
        #pragma unroll
        for (int k = 0; k < SUBS; ++k) sum += __builtin_nontemporal_load(p + k * CW);
        force[i] = sum;
    }
}

// ---------------- fallback (small ws): direct COO scatter -------------------
__global__ void force_kernel(const int* __restrict__ rows, const int* __restrict__ cols,
                             const float* __restrict__ vals, const float* __restrict__ dEflat,
                             float* __restrict__ force) {
    int k = blockIdx.x * blockDim.x + threadIdx.x;
    if (k < NNZ_) {
        float contrib = -vals[k] * dEflat[rows[k]];
        atomicAdd(&force[cols[k]], contrib);
    }
}

extern "C" void kernel_launch(void* const* d_in, const int* in_sizes, int n_in,
                              void* d_out, int out_size, void* d_ws, size_t ws_size,
                              hipStream_t stream) {
    (void)in_sizes; (void)n_in; (void)out_size;
    const float* fps  = (const float*)d_in[0];
    const float* W1   = (const float*)d_in[1];
    const float* b1   = (const float*)d_in[2];
    const float* W2   = (const float*)d_in[3];
    const float* b2   = (const float*)d_in[4];
    const float* W3   = (const float*)d_in[5];
    const float* b3   = (const float*)d_in[6];
    const int*   img  = (const int*)d_in[7];
    const int*   rows = (const int*)d_in[8];
    const int*   cols = (const int*)d_in[9];
    const float* vals = (const float*)d_in[10];

    char* ws = (char*)d_ws;
    // rank pipeline scratch
    int*   g_hist  = (int*)(ws);                     //  5,068,800 B
    int*   g_total = (int*)(ws + 5068800);           //      7,200 B
    int*   g_base  = (int*)(ws + 5076000);           //      7,200 B
    int*   rank    = (int*)(ws + 5083200);           //    720,000 B
    float* dEflat  = (float*)(ws + 5803200);         // 28,800,000 B
    // force pipeline scratch
    int*      binHist  = (int*)(ws + 34603200);      //    928,224 B (NBIN*NSB*4)
    int*      binTotal = (int*)(ws + 35531424);      //        528 B
    int*      binBase  = (int*)(ws + 35531952);      //        532 B (+pad)
    unsigned* bm       = (unsigned*)(ws + 35532496); // 57,600,000 B
    float*    partial  = (float*)(ws + 93132496);    // 17,301,504 B
    const size_t WS_NEEDED = 110434000;

    float* energy = (float*)d_out;                   // [1800]
    float* force  = (float*)d_out + NIMG_;           // [540000]

    const int nOut = NIMG_ + 3 * QTOT;
    zero_kernel<<<(nOut + BLK - 1) / BLK, BLK, 0, stream>>>((float*)d_out, nOut);

    // atom rank (stable argsort of image_idx)
    hist_kernel<<<NB, BLK, 0, stream>>>(img, g_hist);
    scan_blocks_kernel<<<NIMG_, BLK, 0, stream>>>(g_hist, g_total);
    scan_buckets_kernel<<<1, BLK, 0, stream>>>(g_total, g_base);
    rank_kernel<<<NB, BLK, 0, stream>>>(img, g_hist, g_base, rank);

    // per-atom MLP fwd+bwd, energies + ordered jacobian rows
    dim3 gm((QE_ + BLK - 1) / BLK, E_);
    mlp_kernel<<<gm, BLK, 0, stream>>>(fps, W1, b1, W2, b2, W3, b3, img, rank,
                                       energy, dEflat);

    if (ws_size >= WS_NEEDED) {
        fhist_kernel<<<NSB, BLK, 0, stream>>>(cols, binHist);
        fscan_blocks_kernel<<<NBIN, BLK, 0, stream>>>(binHist, binTotal);
        fbase_kernel<<<1, BLK, 0, stream>>>(binTotal, binBase);
        fscatter_kernel<<<NSB, BLK, 0, stream>>>(rows, cols, vals, dEflat,
                                                 binHist, binBase, bm);
        fforce_kernel<<<NBIN * SUBS, BLK, 0, stream>>>(bm, binBase, partial);
        freduce_kernel<<<(3 * QTOT + BLK - 1) / BLK, BLK, 0, stream>>>(partial, force);
    } else {
        force_kernel<<<NNZ_ / BLK, BLK, 0, stream>>>(rows, cols, vals, dEflat, force);
    }
}